// Round 3
// baseline (80.443 us; speedup 1.0000x reference)
//
#include <hip/hip_runtime.h>
#include <hip/hip_bf16.h>

#define HH 8
#define SEQL 4096
#define DD 128
#define NBLK 64
#define LOCAL_B 16
#define MBIAS 12.0f
#define EP_STR 132

typedef __attribute__((ext_vector_type(8))) short bf16x8;
typedef __attribute__((ext_vector_type(4))) float f32x4;
typedef unsigned short ushort_t;

typedef const __attribute__((address_space(1))) unsigned int gu32;
typedef __attribute__((address_space(3))) unsigned int lu32;

__device__ __forceinline__ unsigned short f2bf(float x) {
    union { float f; unsigned u; } a; a.f = x;
    unsigned r = a.u + 0x7FFFu + ((a.u >> 16) & 1u);
    return (unsigned short)(r >> 16);
}

__device__ __forceinline__ unsigned cvtpk_bf16(float lo, float hi) {
    unsigned r;
    asm("v_cvt_pk_bf16_f32 %0, %1, %2" : "=v"(r) : "v"(lo), "v"(hi));
    return r;
}

__device__ __forceinline__ void gload16(const void* src, void* ldsdst) {
    __builtin_amdgcn_global_load_lds((gu32*)src, (lu32*)ldsdst, 16, 0, 0);
}

// ---------------- fused prepass: K f32->bf16 flat; V f32 [H][S][D] -> bf16 Vt [H][D][S] ----------------
#define T_STR 136
__global__ void prep(const float* __restrict__ k, const float* __restrict__ v,
                     ushort_t* __restrict__ kb, ushort_t* __restrict__ vt) {
    __shared__ ushort_t t[64 * T_STR];
    int bid = blockIdx.x;
    int tid = threadIdx.x;
    if (bid < 2048) {
        int idx = (bid * 256 + tid) * 8;
        const float4* s = (const float4*)(k + idx);
        float4 a = s[0], b = s[1];
        union { bf16x8 v8; ushort_t u[8]; } p;
        p.u[0] = f2bf(a.x); p.u[1] = f2bf(a.y); p.u[2] = f2bf(a.z); p.u[3] = f2bf(a.w);
        p.u[4] = f2bf(b.x); p.u[5] = f2bf(b.y); p.u[6] = f2bf(b.z); p.u[7] = f2bf(b.w);
        *(bf16x8*)(kb + idx) = p.v8;
        return;
    }
    int g = bid - 2048;
    int h  = g >> 6;
    int sb = g & 63;
    const float* vp = v + ((size_t)h * SEQL + sb * 64) * DD;
    {
        int col = (tid & 15) * 8;
        #pragma unroll
        for (int it = 0; it < 4; ++it) {
            int row = it * 16 + (tid >> 4);
            const float4* s = (const float4*)(vp + row * DD + col);
            float4 a = s[0], b = s[1];
            union { bf16x8 v8; ushort_t u[8]; } p;
            p.u[0] = f2bf(a.x); p.u[1] = f2bf(a.y); p.u[2] = f2bf(a.z); p.u[3] = f2bf(a.w);
            p.u[4] = f2bf(b.x); p.u[5] = f2bf(b.y); p.u[6] = f2bf(b.z); p.u[7] = f2bf(b.w);
            *(bf16x8*)&t[row * T_STR + col] = p.v8;
        }
    }
    __syncthreads();
    {
        int d = tid >> 1, seg = tid & 1;
        ushort_t* dst = vt + ((size_t)h * DD + d) * SEQL + sb * 64 + seg * 32;
        #pragma unroll
        for (int i = 0; i < 4; ++i) {
            union { bf16x8 v8; ushort_t u[8]; } o;
            #pragma unroll
            for (int e = 0; e < 8; ++e)
                o.u[e] = t[(seg * 32 + i * 8 + e) * T_STR + d];
            *(bf16x8*)(dst + i * 8) = o.v8;
        }
    }
}

// ---------------- main attention kernel ----------------
__global__ __launch_bounds__(256, 2)
void bsattn3(const float* __restrict__ q, const ushort_t* __restrict__ kbuf,
             const ushort_t* __restrict__ vtbuf, const float* __restrict__ scl,
             float* __restrict__ out) {
    const int g  = blockIdx.x;
    const int h  = g & 7;
    const int i0 = g >> 3;
    const int qb = (i0 & 1) ? (i0 >> 1) : (NBLK - 1 - (i0 >> 1));  // 63,0,62,1,...
    const int tid = threadIdx.x;
    const int w  = tid >> 6;
    const int l  = tid & 63;
    const int lr = l & 15;
    const int lg = l >> 4;

    __shared__ char smem[131072];
    // K tiles:  smem + buf*32768          (64 rows x 256B, swizzled)
    // Vt tiles: smem + 65536 + buf*16384  (128 rows x 128B, swizzled)
    // epilogue: reuses smem as float [64][EP_STR]

    const float kappa = scl[0] * 1.44269504088896f;

    const float*    qh = q     + (size_t)h * SEQL * DD;
    const ushort_t* kh = kbuf  + (size_t)h * SEQL * DD;
    const ushort_t* vh = vtbuf + (size_t)h * DD * SEQL;
    float*          oh = out   + (size_t)h * SEQL * DD;

    // Q -> B-fragments, prescaled by kappa (wave w owns q cols 16w..16w+15)
    bf16x8 qf[4];
    {
        const float* qrow = qh + (size_t)(qb * 64 + 16 * w + lr) * DD;
        #pragma unroll
        for (int ks = 0; ks < 4; ++ks) {
            const float4* p4 = (const float4*)(qrow + ks * 32 + lg * 8);
            float4 x = p4[0], y = p4[1];
            union { bf16x8 v8; ushort_t u[8]; } pk;
            pk.u[0] = f2bf(x.x * kappa); pk.u[1] = f2bf(x.y * kappa);
            pk.u[2] = f2bf(x.z * kappa); pk.u[3] = f2bf(x.w * kappa);
            pk.u[4] = f2bf(y.x * kappa); pk.u[5] = f2bf(y.y * kappa);
            pk.u[6] = f2bf(y.z * kappa); pk.u[7] = f2bf(y.w * kappa);
            qf[ks] = pk.v8;
        }
    }

    f32x4 oacc[8];   // O^T: row d = 16dt+4lg+j, col q = lr
    #pragma unroll
    for (int i = 0; i < 8; ++i) oacc[i] = (f32x4){0.f, 0.f, 0.f, 0.f};
    float lrun = 0.f;  // per-lane partial row-sum (q=lr, its 16 k per iter)

    auto stage = [&](int buf, int kb) {
        const char* kbase = (const char*)(kh + (size_t)kb * 64 * DD);
        char* kdst = smem + buf * 32768;
        #pragma unroll
        for (int j = 0; j < 4; ++j) {
            int row  = w * 16 + j * 4 + (l >> 4);
            int colb = ((l & 15) << 4) ^ ((row & 7) << 4);
            gload16(kbase + row * 256 + colb, kdst + (w * 16 + j * 4) * 256);
        }
        const char* vbase = (const char*)vh + (size_t)kb * 128;
        char* vdst = smem + 65536 + buf * 16384;
        #pragma unroll
        for (int j = 0; j < 4; ++j) {
            int d0 = w * 32 + j * 8;
            int d  = d0 + (l >> 3);
            int colb = ((l & 7) << 4) ^ ((d & 7) << 4);
            gload16(vbase + (size_t)d * (SEQL * 2) + colb, vdst + d0 * 128);
        }
    };

    auto compute = [&](int buf, bool diag) {
        const char* kb8 = smem + buf * 32768;
        // S^T = K Q^T : row k = 16ct+4lg+j, col q = lr; C-init = -MBIAS
        f32x4 sacc[4];
        #pragma unroll
        for (int ct = 0; ct < 4; ++ct)
            sacc[ct] = (f32x4){-MBIAS, -MBIAS, -MBIAS, -MBIAS};
        __builtin_amdgcn_s_setprio(1);
        #pragma unroll
        for (int ks = 0; ks < 4; ++ks) {
            #pragma unroll
            for (int ct = 0; ct < 4; ++ct) {
                int row = ct * 16 + lr;
                bf16x8 kf = *(const bf16x8*)(kb8 + row * 256 +
                                             ((ks * 64 + lg * 16) ^ ((row & 7) << 4)));
                sacc[ct] = __builtin_amdgcn_mfma_f32_16x16x32_bf16(kf, qf[ks], sacc[ct], 0, 0, 0);
            }
        }
        __builtin_amdgcn_s_setprio(0);

        // p = exp2(S^T - M); zero masked (diag) entries AFTER exp
        float p[4][4];
        #pragma unroll
        for (int ct = 0; ct < 4; ++ct)
            #pragma unroll
            for (int j = 0; j < 4; ++j)
                p[ct][j] = exp2f(sacc[ct][j]);
        if (diag) {
            #pragma unroll
            for (int ct = 0; ct < 4; ++ct)
                #pragma unroll
                for (int j = 0; j < 4; ++j)
                    if (16 * ct + 4 * lg + j > 16 * w + lr) p[ct][j] = 0.f;
        }
        float rs = 0.f;
        #pragma unroll
        for (int ct = 0; ct < 4; ++ct)
            #pragma unroll
            for (int j = 0; j < 4; ++j) rs += p[ct][j];
        lrun += rs;

        // pack P to bf16 pairs: pk[ct][jj] covers k = 16ct+4lg+{2jj,2jj+1}
        unsigned e0 = cvtpk_bf16(p[0][0], p[0][1]), e1 = cvtpk_bf16(p[0][2], p[0][3]);
        unsigned e2 = cvtpk_bf16(p[2][0], p[2][1]), e3 = cvtpk_bf16(p[2][2], p[2][3]);
        unsigned o0 = cvtpk_bf16(p[1][0], p[1][1]), o1 = cvtpk_bf16(p[1][2], p[1][3]);
        unsigned o2 = cvtpk_bf16(p[3][0], p[3][1]), o3 = cvtpk_bf16(p[3][2], p[3][3]);

        // 2-round butterfly -> B-fragments for PV (see routing derivation)
        const bool selA = (lg >= 2);
        unsigned m0 = selA ? o0 : e0, m1 = selA ? o1 : e1, m2 = selA ? o2 : e2, m3 = selA ? o3 : e3;
        unsigned n0 = selA ? e0 : o0, n1 = selA ? e1 : o1, n2 = selA ? e2 : o2, n3 = selA ? e3 : o3;
        unsigned t0 = __shfl_xor((int)n0, 32), t1 = __shfl_xor((int)n1, 32);
        unsigned t2 = __shfl_xor((int)n2, 32), t3 = __shfl_xor((int)n3, 32);
        const bool wsel = ((lg ^ (lg >> 1)) & 1);
        unsigned w0 = wsel ? m0 : t0, w1 = wsel ? m1 : t1, w2 = wsel ? m2 : t2, w3 = wsel ? m3 : t3;
        unsigned u0 = wsel ? t0 : m0, u1 = wsel ? t1 : m1, u2 = wsel ? t2 : m2, u3 = wsel ? t3 : m3;
        unsigned v0 = __shfl_xor((int)w0, 16), v1 = __shfl_xor((int)w1, 16);
        unsigned v2 = __shfl_xor((int)w2, 16), v3 = __shfl_xor((int)w3, 16);
        const bool bl = lg & 1;
        union { unsigned u[4]; bf16x8 v8; } pb0, pb1;
        pb0.u[0] = bl ? v0 : u0; pb0.u[1] = bl ? v1 : u1;
        pb0.u[2] = bl ? u0 : v0; pb0.u[3] = bl ? u1 : v1;
        pb1.u[0] = bl ? v2 : u2; pb1.u[1] = bl ? v3 : u3;
        pb1.u[2] = bl ? u2 : v2; pb1.u[3] = bl ? u3 : v3;

        // O^T += Vt P : A = Vt rows d, B = P cols q
        const char* vb8 = smem + 65536 + buf * 16384;
        __builtin_amdgcn_s_setprio(1);
        #pragma unroll
        for (int dt = 0; dt < 8; ++dt) {
            int row = dt * 16 + lr;
            bf16x8 vf = *(const bf16x8*)(vb8 + row * 128 + ((lg * 16) ^ ((row & 7) << 4)));
            oacc[dt] = __builtin_amdgcn_mfma_f32_16x16x32_bf16(vf, pb0.v8, oacc[dt], 0, 0, 0);
        }
        #pragma unroll
        for (int dt = 0; dt < 8; ++dt) {
            int row = dt * 16 + lr;
            bf16x8 vf = *(const bf16x8*)(vb8 + row * 128 + ((64 + lg * 16) ^ ((row & 7) << 4)));
            oacc[dt] = __builtin_amdgcn_mfma_f32_16x16x32_bf16(vf, pb1.v8, oacc[dt], 0, 0, 0);
        }
        __builtin_amdgcn_s_setprio(0);
    };

    // iterate active k blocks: vertical-strided tail, then local band, then diagonal
    const int vstart = (7 - h) & 7;
    int lo = qb - (LOCAL_B - 1); if (lo < 0) lo = 0;
    int kb = (vstart <= qb - LOCAL_B) ? vstart : lo;
    int cur = 0;
    stage(0, kb);
    while (kb >= 0) {
        int kn;
        if (kb < lo) { int n = kb + 8; kn = (n <= qb - LOCAL_B) ? n : lo; }
        else if (kb < qb) kn = kb + 1;
        else kn = -1;

        if (kn >= 0) {
            stage(cur ^ 1, kn);
            asm volatile("s_waitcnt vmcnt(8)" ::: "memory");
        } else {
            asm volatile("s_waitcnt vmcnt(0)" ::: "memory");
        }
        __builtin_amdgcn_sched_barrier(0);
        __builtin_amdgcn_s_barrier();
        __builtin_amdgcn_sched_barrier(0);

        compute(cur, kb == qb);

        __builtin_amdgcn_s_barrier();
        cur ^= 1;
        kb = kn;
    }

    // epilogue: finish row sums (reduce across lane-groups), normalize, transpose via LDS
    float tot = lrun;
    tot += __shfl_xor(tot, 16);
    tot += __shfl_xor(tot, 32);
    float rcp = 1.0f / tot;

    float* ep  = (float*)smem;
    float* epw = ep + w * 16 * EP_STR;
    #pragma unroll
    for (int dt = 0; dt < 8; ++dt)
        #pragma unroll
        for (int j = 0; j < 4; ++j)
            epw[lr * EP_STR + dt * 16 + 4 * lg + j] = oacc[dt][j] * rcp;
    __syncthreads();
    {
        int qr  = tid >> 2;
        int seg = tid & 3;
        const float* rp = ep + (qr >> 4) * (16 * EP_STR) + (qr & 15) * EP_STR + seg * 32;
        float* op = oh + (size_t)(qb * 64 + qr) * DD + seg * 32;
        #pragma unroll
        for (int i = 0; i < 8; ++i)
            ((float4*)op)[i] = ((const float4*)rp)[i];
    }
}

extern "C" void kernel_launch(void* const* d_in, const int* in_sizes, int n_in,
                              void* d_out, int out_size, void* d_ws, size_t ws_size,
                              hipStream_t stream) {
    const float* q   = (const float*)d_in[0];
    const float* k   = (const float*)d_in[1];
    const float* v   = (const float*)d_in[2];
    const float* scl = (const float*)d_in[3];
    float* out = (float*)d_out;

    ushort_t* Kb = (ushort_t*)d_ws;                          // 8 MB bf16 K
    ushort_t* Vt = Kb + (size_t)HH * SEQL * DD;              // 8 MB bf16 V^T

    prep<<<dim3(2048 + HH * 64), dim3(256), 0, stream>>>(k, v, Kb, Vt);
    bsattn3<<<dim3(HH * NBLK), dim3(256), 0, stream>>>(q, Kb, Vt, scl, out);
}

// Round 4
// 56.345 us; speedup vs baseline: 1.4277x; 1.4277x over previous
//
#include <hip/hip_runtime.h>
#include <hip/hip_bf16.h>

#define HH 8
#define SEQL 4096
#define DD 128
#define NBLK 64
#define LOCAL_B 16
#define MBIAS 12.0f
#define EP_STR 132

typedef __attribute__((ext_vector_type(8))) short bf16x8;
typedef __attribute__((ext_vector_type(4))) float f32x4;
typedef unsigned short ushort_t;

typedef const __attribute__((address_space(1))) unsigned int gu32;
typedef __attribute__((address_space(3))) unsigned int lu32;

__device__ __forceinline__ unsigned short f2bf(float x) {
    union { float f; unsigned u; } a; a.f = x;
    unsigned r = a.u + 0x7FFFu + ((a.u >> 16) & 1u);
    return (unsigned short)(r >> 16);
}

__device__ __forceinline__ unsigned cvtpk_bf16(float lo, float hi) {
    unsigned r;
    asm("v_cvt_pk_bf16_f32 %0, %1, %2" : "=v"(r) : "v"(lo), "v"(hi));
    return r;
}

__device__ __forceinline__ void gload16(const void* src, void* ldsdst) {
    __builtin_amdgcn_global_load_lds((gu32*)src, (lu32*)ldsdst, 16, 0, 0);
}

// ---------------- fused prepass: K f32->bf16 flat; V f32 [H][S][D] -> bf16 Vt [H][D][S] ----------------
#define T_STR 136
__global__ void prep(const float* __restrict__ k, const float* __restrict__ v,
                     ushort_t* __restrict__ kb, ushort_t* __restrict__ vt) {
    __shared__ ushort_t t[64 * T_STR];
    int bid = blockIdx.x;
    int tid = threadIdx.x;
    if (bid < 2048) {
        int idx = (bid * 256 + tid) * 8;
        const float4* s = (const float4*)(k + idx);
        float4 a = s[0], b = s[1];
        union { bf16x8 v8; ushort_t u[8]; } p;
        p.u[0] = f2bf(a.x); p.u[1] = f2bf(a.y); p.u[2] = f2bf(a.z); p.u[3] = f2bf(a.w);
        p.u[4] = f2bf(b.x); p.u[5] = f2bf(b.y); p.u[6] = f2bf(b.z); p.u[7] = f2bf(b.w);
        *(bf16x8*)(kb + idx) = p.v8;
        return;
    }
    int g = bid - 2048;
    int h  = g >> 6;
    int sb = g & 63;
    const float* vp = v + ((size_t)h * SEQL + sb * 64) * DD;
    {
        int col = (tid & 15) * 8;
        #pragma unroll
        for (int it = 0; it < 4; ++it) {
            int row = it * 16 + (tid >> 4);
            const float4* s = (const float4*)(vp + row * DD + col);
            float4 a = s[0], b = s[1];
            union { bf16x8 v8; ushort_t u[8]; } p;
            p.u[0] = f2bf(a.x); p.u[1] = f2bf(a.y); p.u[2] = f2bf(a.z); p.u[3] = f2bf(a.w);
            p.u[4] = f2bf(b.x); p.u[5] = f2bf(b.y); p.u[6] = f2bf(b.z); p.u[7] = f2bf(b.w);
            *(bf16x8*)&t[row * T_STR + col] = p.v8;
        }
    }
    __syncthreads();
    {
        int d = tid >> 1, seg = tid & 1;
        ushort_t* dst = vt + ((size_t)h * DD + d) * SEQL + sb * 64 + seg * 32;
        #pragma unroll
        for (int i = 0; i < 4; ++i) {
            union { bf16x8 v8; ushort_t u[8]; } o;
            #pragma unroll
            for (int e = 0; e < 8; ++e)
                o.u[e] = t[(seg * 32 + i * 8 + e) * T_STR + d];
            *(bf16x8*)(dst + i * 8) = o.v8;
        }
    }
}

// ---------------- main attention kernel ----------------
__global__ __launch_bounds__(256, 2)
void bsattn4(const float* __restrict__ q, const ushort_t* __restrict__ kbuf,
             const ushort_t* __restrict__ vtbuf, const float* __restrict__ scl,
             float* __restrict__ out) {
    const int g  = blockIdx.x;
    const int h  = g & 7;
    const int i0 = g >> 3;
    const int qb = (i0 < 32) ? (63 - i0) : (i0 - 32);   // g and g+256 share a CU: qb sum = 63
    const int tid = threadIdx.x;
    const int w  = tid >> 6;
    const int l  = tid & 63;
    const int lr = l & 15;
    const int lg = l >> 4;

    __shared__ char smem[65536];
    // K tiles:  smem + buf*16384           (64 rows x 256B, swizzled)
    // Vt tiles: smem + 32768 + buf*16384   (128 rows x 128B, swizzled)
    // epilogue: reuses smem as float [4][16][EP_STR] (33792 B)

    const float kappa = scl[0] * 1.44269504088896f;

    const float*    qh = q     + (size_t)h * SEQL * DD;
    const ushort_t* kh = kbuf  + (size_t)h * SEQL * DD;
    const ushort_t* vh = vtbuf + (size_t)h * DD * SEQL;
    float*          oh = out   + (size_t)h * SEQL * DD;

    // Q -> B-fragments, prescaled by kappa (wave w owns q cols 16w..16w+15)
    bf16x8 qf[4];
    {
        const float* qrow = qh + (size_t)(qb * 64 + 16 * w + lr) * DD;
        #pragma unroll
        for (int ks = 0; ks < 4; ++ks) {
            const float4* p4 = (const float4*)(qrow + ks * 32 + lg * 8);
            float4 x = p4[0], y = p4[1];
            union { bf16x8 v8; ushort_t u[8]; } pk;
            pk.u[0] = f2bf(x.x * kappa); pk.u[1] = f2bf(x.y * kappa);
            pk.u[2] = f2bf(x.z * kappa); pk.u[3] = f2bf(x.w * kappa);
            pk.u[4] = f2bf(y.x * kappa); pk.u[5] = f2bf(y.y * kappa);
            pk.u[6] = f2bf(y.z * kappa); pk.u[7] = f2bf(y.w * kappa);
            qf[ks] = pk.v8;
        }
    }

    f32x4 oacc[8];   // O^T: row d = 16dt+4lg+j, col q = lr
    #pragma unroll
    for (int i = 0; i < 8; ++i) oacc[i] = (f32x4){0.f, 0.f, 0.f, 0.f};
    float lrun = 0.f;  // per-lane partial row-sum

    auto stage = [&](int buf, int kb) {
        const char* kbase = (const char*)(kh + (size_t)kb * 64 * DD);
        char* kdst = smem + buf * 16384;
        #pragma unroll
        for (int j = 0; j < 4; ++j) {
            int row  = w * 16 + j * 4 + (l >> 4);
            int colb = ((l & 15) << 4) ^ ((row & 7) << 4);
            gload16(kbase + row * 256 + colb, kdst + (w * 16 + j * 4) * 256);
        }
        const char* vbase = (const char*)vh + (size_t)kb * 128;
        char* vdst = smem + 32768 + buf * 16384;
        #pragma unroll
        for (int j = 0; j < 4; ++j) {
            int d0 = w * 32 + j * 8;
            int d  = d0 + (l >> 3);
            int colb = ((l & 7) << 4) ^ ((d & 7) << 4);
            gload16(vbase + (size_t)d * (SEQL * 2) + colb, vdst + d0 * 128);
        }
    };

    auto compute = [&](int buf, bool diag) {
        const char* kb8 = smem + buf * 16384;
        // S^T = K Q^T : row k = 16ct+4lg+j, col q = lr; C-init = -MBIAS
        f32x4 sacc[4];
        #pragma unroll
        for (int ct = 0; ct < 4; ++ct)
            sacc[ct] = (f32x4){-MBIAS, -MBIAS, -MBIAS, -MBIAS};
        __builtin_amdgcn_s_setprio(1);
        #pragma unroll
        for (int ks = 0; ks < 4; ++ks) {
            #pragma unroll
            for (int ct = 0; ct < 4; ++ct) {
                int row = ct * 16 + lr;
                bf16x8 kf = *(const bf16x8*)(kb8 + row * 256 +
                                             ((ks * 64 + lg * 16) ^ ((row & 7) << 4)));
                sacc[ct] = __builtin_amdgcn_mfma_f32_16x16x32_bf16(kf, qf[ks], sacc[ct], 0, 0, 0);
            }
        }
        __builtin_amdgcn_s_setprio(0);

        // p = exp2(S^T - M); zero masked (diag) entries AFTER exp
        float p[4][4];
        #pragma unroll
        for (int ct = 0; ct < 4; ++ct)
            #pragma unroll
            for (int j = 0; j < 4; ++j)
                p[ct][j] = exp2f(sacc[ct][j]);
        if (diag) {
            #pragma unroll
            for (int ct = 0; ct < 4; ++ct)
                #pragma unroll
                for (int j = 0; j < 4; ++j)
                    if (16 * ct + 4 * lg + j > 16 * w + lr) p[ct][j] = 0.f;
        }
        float rs = 0.f;
        #pragma unroll
        for (int ct = 0; ct < 4; ++ct)
            #pragma unroll
            for (int j = 0; j < 4; ++j) rs += p[ct][j];
        lrun += rs;

        // pack P to bf16 pairs
        unsigned e0 = cvtpk_bf16(p[0][0], p[0][1]), e1 = cvtpk_bf16(p[0][2], p[0][3]);
        unsigned e2 = cvtpk_bf16(p[2][0], p[2][1]), e3 = cvtpk_bf16(p[2][2], p[2][3]);
        unsigned o0 = cvtpk_bf16(p[1][0], p[1][1]), o1 = cvtpk_bf16(p[1][2], p[1][3]);
        unsigned o2 = cvtpk_bf16(p[3][0], p[3][1]), o3 = cvtpk_bf16(p[3][2], p[3][3]);

        // 2-round butterfly -> B-fragments for PV
        const bool selA = (lg >= 2);
        unsigned m0 = selA ? o0 : e0, m1 = selA ? o1 : e1, m2 = selA ? o2 : e2, m3 = selA ? o3 : e3;
        unsigned n0 = selA ? e0 : o0, n1 = selA ? e1 : o1, n2 = selA ? e2 : o2, n3 = selA ? e3 : o3;
        unsigned t0 = __shfl_xor((int)n0, 32), t1 = __shfl_xor((int)n1, 32);
        unsigned t2 = __shfl_xor((int)n2, 32), t3 = __shfl_xor((int)n3, 32);
        const bool wsel = ((lg ^ (lg >> 1)) & 1);
        unsigned w0 = wsel ? m0 : t0, w1 = wsel ? m1 : t1, w2 = wsel ? m2 : t2, w3 = wsel ? m3 : t3;
        unsigned u0 = wsel ? t0 : m0, u1 = wsel ? t1 : m1, u2 = wsel ? t2 : m2, u3 = wsel ? t3 : m3;
        unsigned v0 = __shfl_xor((int)w0, 16), v1 = __shfl_xor((int)w1, 16);
        unsigned v2 = __shfl_xor((int)w2, 16), v3 = __shfl_xor((int)w3, 16);
        const bool bl = lg & 1;
        union { unsigned u[4]; bf16x8 v8; } pb0, pb1;
        pb0.u[0] = bl ? v0 : u0; pb0.u[1] = bl ? v1 : u1;
        pb0.u[2] = bl ? u0 : v0; pb0.u[3] = bl ? u1 : v1;
        pb1.u[0] = bl ? v2 : u2; pb1.u[1] = bl ? v3 : u3;
        pb1.u[2] = bl ? u2 : v2; pb1.u[3] = bl ? u3 : v3;

        // O^T += Vt P
        const char* vb8 = smem + 32768 + buf * 16384;
        __builtin_amdgcn_s_setprio(1);
        #pragma unroll
        for (int dt = 0; dt < 8; ++dt) {
            int row = dt * 16 + lr;
            bf16x8 vf = *(const bf16x8*)(vb8 + row * 128 + ((lg * 16) ^ ((row & 7) << 4)));
            oacc[dt] = __builtin_amdgcn_mfma_f32_16x16x32_bf16(vf, pb0.v8, oacc[dt], 0, 0, 0);
        }
        #pragma unroll
        for (int dt = 0; dt < 8; ++dt) {
            int row = dt * 16 + lr;
            bf16x8 vf = *(const bf16x8*)(vb8 + row * 128 + ((64 + lg * 16) ^ ((row & 7) << 4)));
            oacc[dt] = __builtin_amdgcn_mfma_f32_16x16x32_bf16(vf, pb1.v8, oacc[dt], 0, 0, 0);
        }
        __builtin_amdgcn_s_setprio(0);
    };

    // iterate active k blocks: vertical-strided tail, then local band, then diagonal
    const int vstart = (7 - h) & 7;
    int lo = qb - (LOCAL_B - 1); if (lo < 0) lo = 0;
    int kb = (vstart <= qb - LOCAL_B) ? vstart : lo;
    int cur = 0;
    stage(0, kb);
    while (kb >= 0) {
        int kn;
        if (kb < lo) { int n = kb + 8; kn = (n <= qb - LOCAL_B) ? n : lo; }
        else if (kb < qb) kn = kb + 1;
        else kn = -1;

        if (kn >= 0) {
            stage(cur ^ 1, kn);
            asm volatile("s_waitcnt vmcnt(8)" ::: "memory");
        } else {
            asm volatile("s_waitcnt vmcnt(0)" ::: "memory");
        }
        __builtin_amdgcn_sched_barrier(0);
        __builtin_amdgcn_s_barrier();
        __builtin_amdgcn_sched_barrier(0);

        compute(cur, kb == qb);

        __builtin_amdgcn_s_barrier();
        cur ^= 1;
        kb = kn;
    }

    // epilogue: finish row sums, normalize, transpose via LDS for coalesced stores
    float tot = lrun;
    tot += __shfl_xor(tot, 16);
    tot += __shfl_xor(tot, 32);
    float rcp = 1.0f / tot;

    float* ep  = (float*)smem;
    float* epw = ep + w * 16 * EP_STR;
    #pragma unroll
    for (int dt = 0; dt < 8; ++dt)
        #pragma unroll
        for (int j = 0; j < 4; ++j)
            epw[lr * EP_STR + dt * 16 + 4 * lg + j] = oacc[dt][j] * rcp;
    __syncthreads();
    {
        int qr  = tid >> 2;
        int seg = tid & 3;
        const float* rp = ep + (qr >> 4) * (16 * EP_STR) + (qr & 15) * EP_STR + seg * 32;
        float* op = oh + (size_t)(qb * 64 + qr) * DD + seg * 32;
        #pragma unroll
        for (int i = 0; i < 8; ++i)
            ((float4*)op)[i] = ((const float4*)rp)[i];
    }
}

extern "C" void kernel_launch(void* const* d_in, const int* in_sizes, int n_in,
                              void* d_out, int out_size, void* d_ws, size_t ws_size,
                              hipStream_t stream) {
    const float* q   = (const float*)d_in[0];
    const float* k   = (const float*)d_in[1];
    const float* v   = (const float*)d_in[2];
    const float* scl = (const float*)d_in[3];
    float* out = (float*)d_out;

    ushort_t* Kb = (ushort_t*)d_ws;                          // 8 MB bf16 K
    ushort_t* Vt = Kb + (size_t)HH * SEQL * DD;              // 8 MB bf16 V^T

    prep<<<dim3(2048 + HH * 64), dim3(256), 0, stream>>>(k, v, Kb, Vt);
    bsattn4<<<dim3(HH * NBLK), dim3(256), 0, stream>>>(q, Kb, Vt, scl, out);
}